// Round 19
// baseline (123.114 us; speedup 1.0000x reference)
//
#include <hip/hip_runtime.h>
#include <math.h>

#define B_   32
#define C_   32
#define T_   1024
#define NF_  33
#define F2_  66      // NF*2
#define FD_  2112    // C_*F2_
#define FDH_ 1056    // FD_/2 (u32)
#define NW_  961
#define MLP_ 256
#define HID_ 256
#define HH_  128
#define TN_  32
#define NT_  31      // ceil(961/32)

#define PI_F     3.14159265358979323846f
#define LN2_F    0.69314718055994530942f
#define L2E2_F   2.88539008177792681472f   // 2*log2(e)

typedef unsigned short u16;
typedef unsigned int   u32;
typedef __attribute__((ext_vector_type(8))) short bf16x8;
typedef __attribute__((ext_vector_type(4))) float f32x4;

__device__ __forceinline__ u16 f2bf(float f) {
    u32 u = __float_as_uint(f);
    u = u + 0x7FFFu + ((u >> 16) & 1u);   // RNE
    return (u16)(u >> 16);
}
// pack (lo, hi) -> u32{bf16(hi)<<16 | bf16(lo)}, RNE, single instruction
__device__ __forceinline__ u32 pk_bf16(float lo, float hi) {
    u32 r;
    asm("v_cvt_pk_bf16_f32 %0, %1, %2" : "=v"(r) : "v"(lo), "v"(hi));
    return r;
}
__device__ __forceinline__ void gload16(const void* g, void* l) {
    __builtin_amdgcn_global_load_lds(
        (const __attribute__((address_space(1))) void*)g,
        (__attribute__((address_space(3))) void*)l, 16, 0, 0);
}
__device__ __forceinline__ float ftanh(float x) {
    float z = __builtin_amdgcn_exp2f(x * L2E2_F);
    return 1.f - 2.f * __builtin_amdgcn_rcpf(z + 1.f);
}
__device__ __forceinline__ float flog1p(float x) {
    return __builtin_amdgcn_logf(1.f + x) * LN2_F;   // v_log_f32 is log2
}
// atan2(y,x)/pi, 4-term poly, max err ~3e-6 (pi units) -- << bf16 quantum
__device__ __forceinline__ float fatan2pi(float y, float x) {
    const float ay = fabsf(y), ax = fabsf(x);
    const float mn = fminf(ay, ax), mx = fmaxf(ay, ax);
    float t = mn * __builtin_amdgcn_rcpf(mx);
    t = (mx == 0.f) ? 0.f : t;
    const float s = t * t;
    float p = -0.027097f;
    p = fmaf(p, s,  0.057337f);
    p = fmaf(p, s, -0.105130f);
    p = fmaf(p, s,  0.318268f);
    p *= t;
    p = (ay > ax) ? 0.5f - p : p;
    p = (x < 0.f) ? 1.0f - p : p;
    return copysignf(p, y);
}

// ---------------------------------------------------------------------------
// prep: Wp -> bf16 with K-PERMUTATION matching feat's coalesced layout:
//   src k = c*66 + q (q=2f+p):  kp = (q<64) ? 64c+q : 2048 + 2c + (q-64)
// W1/W2 -> plain bf16 hi. block 176: softmax.
// ---------------------------------------------------------------------------
__global__ __launch_bounds__(256) void prep_kernel(
        const float* __restrict__ Wp, const float* __restrict__ W1,
        const float* __restrict__ W2, const float* __restrict__ agg,
        u16* __restrict__ WpP, u16* __restrict__ W1H, u16* __restrict__ W2H,
        float* __restrict__ wts) {
    const int blk = blockIdx.x;
    const int tid = threadIdx.x;
    if (blk < 128) {
        const int total = MLP_ * FD_;
        for (int i = blk * 256 + tid; i < total; i += 128 * 256) {
            const int n = i / FD_;
            const int k = i - n * FD_;
            const int c = k / F2_;
            const int q = k - c * F2_;
            const int kp = (q < 64) ? (c * 64 + q) : (2048 + 2 * c + (q - 64));
            WpP[(size_t)n * FD_ + kp] = f2bf(Wp[i]);
        }
    } else if (blk < 160) {
        const int total = HID_ * MLP_;
        for (int i = (blk - 128) * 256 + tid; i < total; i += 32 * 256)
            W1H[i] = f2bf(W1[i]);
    } else if (blk < 176) {
        const int total = HH_ * HID_;
        for (int i = (blk - 160) * 256 + tid; i < total; i += 16 * 256)
            W2H[i] = f2bf(W2[i]);
    } else {
        __shared__ float red[256];
        float mx = -INFINITY;
        for (int i = tid; i < NW_; i += 256) mx = fmaxf(mx, agg[i]);
        red[tid] = mx; __syncthreads();
        for (int s = 128; s > 0; s >>= 1) {
            if (tid < s) red[tid] = fmaxf(red[tid], red[tid + s]);
            __syncthreads();
        }
        mx = red[0]; __syncthreads();
        float sm = 0.f;
        for (int i = tid; i < NW_; i += 256) sm += expf(agg[i] - mx);
        red[tid] = sm; __syncthreads();
        for (int s = 128; s > 0; s >>= 1) {
            if (tid < s) red[tid] += red[tid + s];
            __syncthreads();
        }
        const float inv = 1.f / red[0];
        for (int i = tid; i < NW_; i += 256) wts[i] = expf(agg[i] - mx) * inv;
    }
}

// ---------------------------------------------------------------------------
// feat v6: SLIDING DFT, NO basisT table. Init DFT uses a register twiddle
// rotation w_k = (w1)^k (w1 = stab[tf] = e^{-i pi f/32}); exactly periodic,
// drift ~4e-6 rel << bf16 quantum. LDS = 3.6KB -> occupancy limited only by
// threads (8 blocks/CU). Coalesced K-permuted store layout (round-18).
// ---------------------------------------------------------------------------
__global__ __launch_bounds__(256) void feat_kernel(const float* __restrict__ x,
                                                   u32* __restrict__ featP) {
    const int n0 = blockIdx.x * TN_;
    const int cg = blockIdx.y;
    const int bb = blockIdx.z;
    const int tid = threadIdx.x;
    const int tf = tid & 31;     // bin 0..31
    const int c8 = tid >> 5;     // channel-in-group 0..7
    const int c  = cg * 8 + c8;

    __shared__ float2 stab[64];
    __shared__ float xs[8][96];

    if (tid < 64) {
        float s, cc;
        sincosf(-PI_F * (float)tid / 32.0f, &s, &cc);
        stab[tid] = make_float2(cc, s);   // e^{-i pi tid/32}
    }
    if (tid < 192) {
        const int cs = tid / 24, q = tid % 24;
        const int t0 = n0 + q * 4;
        const float* xb = x + ((size_t)bb * C_ + cg * 8 + cs) * T_;
        float4 v;
        if (t0 + 3 < T_) {
            v = *(const float4*)(xb + t0);
        } else {
            v.x = (t0 + 0 < T_) ? xb[t0 + 0] : 0.f;
            v.y = (t0 + 1 < T_) ? xb[t0 + 1] : 0.f;
            v.z = (t0 + 2 < T_) ? xb[t0 + 2] : 0.f;
            v.w = 0.f;
        }
        *(float4*)&xs[cs][q * 4] = v;
    }
    __syncthreads();

    const size_t rowb = (size_t)bb * NW_;

    // phase 1: bins 0..31, sliding across 32 windows
    {
        const float2 w1 = stab[tf];           // e^{-i pi f/32}
        float re = 0.f, im = 0.f;
        float wc = 1.f, ws = 0.f;             // w_k, rotated by w1 each tap
#pragma unroll
        for (int k = 0; k < 64; ++k) {
            const float xv = xs[c8][k];
            re = fmaf(xv, wc, re);
            im = fmaf(xv, ws, im);
            const float nwc = wc * w1.x - ws * w1.y;
            ws = fmaf(wc, w1.y, ws * w1.x);
            wc = nwc;
        }
        const float cx = w1.x, sx = -w1.y;    // slide twiddle e^{+i pi f/32}

        u32* fp = featP + (rowb + n0) * FDH_ + (c << 5) + tf;
        const int nw = (NW_ - n0 < TN_) ? (NW_ - n0) : TN_;
        for (int j = 0; j < nw; ++j) {
            const float r   = __builtin_amdgcn_sqrtf(fmaf(re, re, im * im));
            const float mag = flog1p(r);
            const float ph  = fatan2pi(im, re);
            *fp = pk_bf16(mag, ph);
            fp += FDH_;
            const float tre = re - xs[c8][j] + xs[c8][j + 64];
            re = tre * cx - im * sx;
            im = tre * sx + im * cx;
        }
    }

    // phase 2: Nyquist bin -> tail block [row][1024 + c]
    {
        const int j   = tid & 31;
        const int c8n = tid >> 5;
        const int gn  = n0 + j;
        if (gn < NW_) {
            float s = 0.f;
#pragma unroll
            for (int k = 0; k < 32; ++k)
                s += xs[c8n][j + 2 * k] - xs[c8n][j + 2 * k + 1];
            const float a = flog1p(fabsf(s));
            const float p = (__float_as_uint(s) >> 31) ? 1.0f : 0.0f;
            featP[(rowb + gn) * FDH_ + 1024 + cg * 8 + c8n] = pk_bf16(a, p);
        }
    }
}

// ---------------------------------------------------------------------------
// gemm64 (round-17, validated): proj GEMM, BK=64, BM=128 x BN=256, 512 thr.
// 3-buffer depth-2 counted-vmcnt, STEPB=48KB, LDS=144KB, 33 K-steps.
// ---------------------------------------------------------------------------
__global__ __launch_bounds__(512, 1) void gemm64_kernel(
        const u16* __restrict__ A, const u16* __restrict__ BH,
        const float* __restrict__ bias, float scale,
        u16* __restrict__ outH, int Mvalid, int Kd) {
    constexpr int STEPB = 16384 + 32768;    // A 16K | B 32K
    __shared__ char lds[3 * STEPB];         // 147456

    const int bm = blockIdx.x;
    const int tid = threadIdx.x;
    const int lane = tid & 63, w = tid >> 6;
    const int wr = w >> 2, wc = w & 3;      // 2 x 4 waves of 64x64
    const int m0 = bm * 128;

    f32x4 acc[4][4];
#pragma unroll
    for (int i = 0; i < 4; ++i)
#pragma unroll
        for (int j = 0; j < 4; ++j) acc[i][j] = (f32x4){0.f, 0.f, 0.f, 0.f};

    const size_t rs = (size_t)Kd * 2;
    const char* gA = (const char*)A + (size_t)m0 * rs;
    const char* gB = (const char*)BH;

    auto st1 = [&](const char* g, char* l, int idx) {
        const int row = idx >> 3;
        const int kc  = (idx & 7) ^ ((row >> 1) & 7);
        gload16(g + (size_t)row * rs + (size_t)(kc << 4), l + idx * 16);
    };
    auto stage = [&](int buf, int t) {
        const size_t k0b = (size_t)t << 7;          // t*128 bytes
        char* lb = lds + buf * STEPB;
        st1(gA + k0b, lb, tid);
        st1(gA + k0b, lb, tid + 512);
        st1(gB + k0b, lb + 16384, tid);
        st1(gB + k0b, lb + 16384, tid + 512);
        st1(gB + k0b, lb + 16384, tid + 1024);
        st1(gB + k0b, lb + 16384, tid + 1536);
    };

    const int q   = lane >> 4;
    const int ra_ = wr * 64 + (lane & 15);
    const int rb_ = wc * 64 + (lane & 15);
    const int s3a = (ra_ >> 1) & 7;
    const int s3b = (rb_ >> 1) & 7;
    const int ab0 = ra_ * 128 + (((0 * 4 + q) ^ s3a) << 4);
    const int ab1 = ra_ * 128 + (((1 * 4 + q) ^ s3a) << 4);
    const int bb0 = rb_ * 128 + (((0 * 4 + q) ^ s3b) << 4);
    const int bb1 = rb_ * 128 + (((1 * 4 + q) ^ s3b) << 4);

    const int nt = Kd >> 6;   // 33

    stage(0, 0);
    stage(1, 1);

    int cur = 0;
    for (int t = 0; t < nt; ++t) {
        if (t + 1 < nt)
            asm volatile("s_waitcnt vmcnt(6)" ::: "memory");
        else
            asm volatile("s_waitcnt vmcnt(0)" ::: "memory");
        __builtin_amdgcn_sched_barrier(0);
        __builtin_amdgcn_s_barrier();
        asm volatile("" ::: "memory");

        int pf = cur + 2; if (pf >= 3) pf -= 3;
        if (t + 2 < nt) stage(pf, t + 2);

        const char* lb = lds + cur * STEPB;
        bf16x8 a0[4], a1[4], b0[4], b1[4];
#pragma unroll
        for (int f = 0; f < 4; ++f) {
            a0[f] = *(const bf16x8*)(lb + ab0 + f * 2048);
            a1[f] = *(const bf16x8*)(lb + ab1 + f * 2048);
            b0[f] = *(const bf16x8*)(lb + 16384 + bb0 + f * 2048);
            b1[f] = *(const bf16x8*)(lb + 16384 + bb1 + f * 2048);
        }
        __builtin_amdgcn_s_setprio(1);
#pragma unroll
        for (int fm = 0; fm < 4; ++fm)
#pragma unroll
            for (int fn = 0; fn < 4; ++fn)
                acc[fm][fn] = __builtin_amdgcn_mfma_f32_16x16x32_bf16(a0[fm], b0[fn], acc[fm][fn], 0, 0, 0);
#pragma unroll
        for (int fm = 0; fm < 4; ++fm)
#pragma unroll
            for (int fn = 0; fn < 4; ++fn)
                acc[fm][fn] = __builtin_amdgcn_mfma_f32_16x16x32_bf16(a1[fm], b1[fn], acc[fm][fn], 0, 0, 0);
        __builtin_amdgcn_s_setprio(0);
        ++cur; if (cur >= 3) cur -= 3;
    }

    float bv[4];
#pragma unroll
    for (int fn = 0; fn < 4; ++fn) bv[fn] = bias[wc * 64 + fn * 16 + (lane & 15)];
#pragma unroll
    for (int fm = 0; fm < 4; ++fm) {
        const int rbase = m0 + wr * 64 + fm * 16 + (lane >> 4) * 4;
#pragma unroll
        for (int fn = 0; fn < 4; ++fn) {
            const int col = wc * 64 + fn * 16 + (lane & 15);
#pragma unroll
            for (int r = 0; r < 4; ++r) {
                const int row = rbase + r;
                if (row < Mvalid) {
                    const float v = ftanh(acc[fm][fn][r] + bv[fn]) * scale;
                    outH[(size_t)row * 256 + col] = f2bf(v);
                }
            }
        }
    }
}

// ---------------------------------------------------------------------------
// mlp_tail: FUSED h1 GEMM + h2 GEMM + weighted reduction (round-16, proven).
// ---------------------------------------------------------------------------
__global__ __launch_bounds__(512, 1) void mlp_tail_kernel(
        const u16* __restrict__ A, const u16* __restrict__ W1Hp,
        const float* __restrict__ b1, const u16* __restrict__ W2Hp,
        const float* __restrict__ b2, const float* __restrict__ Wout,
        const float* __restrict__ bout, const float* __restrict__ wts,
        float* __restrict__ partial, int Mvalid) {
    constexpr int STEPB = 8192 + 16384;     // phase-1 step: A 8K | B 16K
    constexpr int OFFX  = 3 * STEPB;        // 73728
    __shared__ char lds[OFFX + 65536];      // 139264

    const int bm = blockIdx.x;
    const int tid = threadIdx.x;
    const int lane = tid & 63, w = tid >> 6;
    const int m0 = bm * 128;
    const size_t rs = 512;                  // K=256 rows, bytes

    // ================= phase 1: h1 = tanh(proj @ W1^T + b1) =================
    {
        const int wr = w >> 2, wc = w & 3;
        f32x4 acc[4][4];
#pragma unroll
        for (int i = 0; i < 4; ++i)
#pragma unroll
            for (int j = 0; j < 4; ++j) acc[i][j] = (f32x4){0.f, 0.f, 0.f, 0.f};

        const char* gA = (const char*)A + (size_t)m0 * rs;
        const char* gB = (const char*)W1Hp;

        auto st1 = [&](const char* g, char* l, int idx) {
            const int row = idx >> 2;
            const int kc  = (idx & 3) ^ ((row >> 1) & 3);
            gload16(g + (size_t)row * rs + (size_t)(kc << 4), l + idx * 16);
        };
        auto stage = [&](int buf, int t) {
            const size_t k0b = (size_t)t << 6;
            char* lb = lds + buf * STEPB;
            st1(gA + k0b, lb, tid);
            st1(gB + k0b, lb + 8192, tid);
            st1(gB + k0b, lb + 8192, tid + 512);
        };

        const int ra_ = wr * 64 + (lane & 15);
        const int rb_ = wc * 64 + (lane & 15);
        const int q   = lane >> 4;
        const int abase = ra_ * 64 + ((q ^ ((ra_ >> 1) & 3)) << 4);
        const int bbase = rb_ * 64 + ((q ^ ((rb_ >> 1) & 3)) << 4);

        stage(0, 0);
        stage(1, 1);

        int cur = 0;
        for (int t = 0; t < 8; ++t) {
            if (t + 1 < 8)
                asm volatile("s_waitcnt vmcnt(3)" ::: "memory");
            else
                asm volatile("s_waitcnt vmcnt(0)" ::: "memory");
            __builtin_amdgcn_sched_barrier(0);
            __builtin_amdgcn_s_barrier();
            asm volatile("" ::: "memory");

            int pf = cur + 2; if (pf >= 3) pf -= 3;
            if (t + 2 < 8) stage(pf, t + 2);

            const char* lb = lds + cur * STEPB;
            bf16x8 a4[4], b4[4];
#pragma unroll
            for (int f = 0; f < 4; ++f) {
                a4[f] = *(const bf16x8*)(lb + abase + f * 1024);
                b4[f] = *(const bf16x8*)(lb + 8192 + bbase + f * 1024);
            }
            __builtin_amdgcn_s_setprio(1);
#pragma unroll
            for (int fm = 0; fm < 4; ++fm)
#pragma unroll
                for (int fn = 0; fn < 4; ++fn)
                    acc[fm][fn] = __builtin_amdgcn_mfma_f32_16x16x32_bf16(a4[fm], b4[fn], acc[fm][fn], 0, 0, 0);
            __builtin_amdgcn_s_setprio(0);
            ++cur; if (cur >= 3) cur -= 3;
        }

        float bv[4];
#pragma unroll
        for (int fn = 0; fn < 4; ++fn) bv[fn] = b1[wc * 64 + fn * 16 + (lane & 15)];
#pragma unroll
        for (int fm = 0; fm < 4; ++fm) {
#pragma unroll
            for (int fn = 0; fn < 4; ++fn) {
                const int col = wc * 64 + fn * 16 + (lane & 15);
                const int cpart = ((col >> 5) << 6) + ((col & 7) * 2);
                const int kc = (col >> 3) & 3;
#pragma unroll
                for (int r = 0; r < 4; ++r) {
                    const int row = wr * 64 + fm * 16 + (lane >> 4) * 4 + r;
                    const float v = ftanh(acc[fm][fn][r] + bv[fn]);
                    const int byt = row * 512 + cpart + ((kc ^ ((row >> 1) & 3)) << 4);
                    *(u16*)(lds + OFFX + byt) = f2bf(v);
                }
            }
        }
    }
    __syncthreads();   // full drain: X visible to all waves

    // ================= phase 2: h2 = tanh(h1 @ W2^T + b2) =================
    f32x4 acc2[4][4];
#pragma unroll
    for (int i = 0; i < 4; ++i)
#pragma unroll
        for (int j = 0; j < 4; ++j) acc2[i][j] = (f32x4){0.f, 0.f, 0.f, 0.f};

    const int wr2 = (w >> 1) & 1, wc2 = w & 1;   // meaningful for w<4
    {
        const char* gB2 = (const char*)W2Hp;
        auto st2 = [&](int buf, int t) {
            const size_t k0b = (size_t)t << 6;
            const int row = tid >> 2;                 // 0..127
            const int kc  = (tid & 3) ^ ((row >> 1) & 3);
            gload16(gB2 + (size_t)row * rs + k0b + (size_t)(kc << 4),
                    lds + buf * STEPB + tid * 16);
        };
        st2(0, 0);
        st2(1, 1);

        const int q = lane >> 4;
        const int rb = wc2 * 64 + (lane & 15);
        const int bbase = rb * 64 + ((q ^ ((rb >> 1) & 3)) << 4);
        const int ra = wr2 * 64 + (lane & 15);
        const int abase = ra * 512 + ((q ^ ((ra >> 1) & 3)) << 4);

        int cur = 0;
        for (int t = 0; t < 8; ++t) {
            if (t + 1 < 8)
                asm volatile("s_waitcnt vmcnt(1)" ::: "memory");
            else
                asm volatile("s_waitcnt vmcnt(0)" ::: "memory");
            __builtin_amdgcn_sched_barrier(0);
            __builtin_amdgcn_s_barrier();
            asm volatile("" ::: "memory");

            int pf = cur + 2; if (pf >= 3) pf -= 3;
            if (t + 2 < 8) st2(pf, t + 2);

            if (w < 4) {
                const char* lb = lds + cur * STEPB;
                bf16x8 a4[4], b4[4];
#pragma unroll
                for (int f = 0; f < 4; ++f) {
                    a4[f] = *(const bf16x8*)(lds + OFFX + abase + f * 8192 + t * 64);
                    b4[f] = *(const bf16x8*)(lb + bbase + f * 1024);
                }
                __builtin_amdgcn_s_setprio(1);
#pragma unroll
                for (int fm = 0; fm < 4; ++fm)
#pragma unroll
                    for (int fn = 0; fn < 4; ++fn)
                        acc2[fm][fn] = __builtin_amdgcn_mfma_f32_16x16x32_bf16(a4[fm], b4[fn], acc2[fm][fn], 0, 0, 0);
                __builtin_amdgcn_s_setprio(0);
            }
            ++cur; if (cur >= 3) cur -= 3;
        }
    }

    // ================= phase 3: weighted reduction =================
    __syncthreads();
    float* rsum = (float*)lds;               // [128][2]
    float* red  = (float*)(lds + 1024);      // [256]

    if (w < 4) {
        float bv[4], wv[4];
#pragma unroll
        for (int fn = 0; fn < 4; ++fn) {
            const int col = wc2 * 64 + fn * 16 + (lane & 15);
            bv[fn] = b2[col];
            wv[fn] = Wout[col];
        }
#pragma unroll
        for (int fm = 0; fm < 4; ++fm) {
#pragma unroll
            for (int r = 0; r < 4; ++r) {
                float c = 0.f;
#pragma unroll
                for (int fn = 0; fn < 4; ++fn)
                    c += ftanh(acc2[fm][fn][r] + bv[fn]) * wv[fn];
                c += __shfl_xor(c, 1);
                c += __shfl_xor(c, 2);
                c += __shfl_xor(c, 4);
                c += __shfl_xor(c, 8);
                if ((lane & 15) == 0)
                    rsum[(wr2 * 64 + fm * 16 + (lane >> 4) * 4 + r) * 2 + wc2] = c;
            }
        }
    }
    __syncthreads();

    const float bO = bout[0];
    float val = 0.f;
    int rowb = -1;
    if (tid < 128) {
        const int gr = m0 + tid;
        if (gr < Mvalid) {
            const float dot = rsum[tid * 2] + rsum[tid * 2 + 1] + bO;
            rowb = gr / NW_;
            val = dot * wts[gr - rowb * NW_];
        }
    }
    __syncthreads();

    const int bFirst = m0 / NW_;
    if (tid < 256) red[tid] = (tid < 128 && rowb == bFirst) ? val : 0.f;
    __syncthreads();
    for (int s = 128; s > 0; s >>= 1) {
        if (tid < s) red[tid] += red[tid + s];
        __syncthreads();
    }
    if (tid == 0) partial[bm * 2] = red[0];
    __syncthreads();
    if (tid < 256) red[tid] = (tid < 128 && rowb == bFirst + 1) ? val : 0.f;
    __syncthreads();
    for (int s = 128; s > 0; s >>= 1) {
        if (tid < s) red[tid] += red[tid + s];
        __syncthreads();
    }
    if (tid == 0) partial[bm * 2 + 1] = red[0];
}

// ---------------------------------------------------------------------------
// finred: out[b0+b] = fixed-order sum of partial slots spanning batch b.
// ---------------------------------------------------------------------------
__global__ __launch_bounds__(64) void finred_kernel(const float* __restrict__ partial,
                                                    float* __restrict__ out,
                                                    int nbat, int nblocks) {
    const int b = threadIdx.x;
    if (b >= nbat) return;
    int lo = (b * NW_) / 128;
    int hi = ((b + 1) * NW_ - 1) / 128;
    if (hi > nblocks - 1) hi = nblocks - 1;
    float s = 0.f;
    for (int bm = lo; bm <= hi; ++bm) {
        const int slot = ((bm * 128) / NW_ == b) ? 0 : 1;
        s += partial[bm * 2 + slot];
    }
    out[b] = s;
}

// ---------------------------------------------------------------------------
extern "C" void kernel_launch(void* const* d_in, const int* in_sizes, int n_in,
                              void* d_out, int out_size, void* d_ws, size_t ws_size,
                              hipStream_t stream) {
    const float* x    = (const float*)d_in[0];
    const float* Wp   = (const float*)d_in[1];
    const float* bp   = (const float*)d_in[2];
    const float* W1   = (const float*)d_in[3];
    const float* b1   = (const float*)d_in[4];
    const float* W2   = (const float*)d_in[5];
    const float* b2   = (const float*)d_in[6];
    const float* Wout = (const float*)d_in[7];
    const float* bout = (const float*)d_in[8];
    const float* agg  = (const float*)d_in[9];
    float* out = (float*)d_out;

    char* wsb = (char*)d_ws;
    size_t off = 0;
    auto ra = [](size_t b) { return (b + 255) & ~(size_t)255; };
    auto alloc = [&](size_t bytes) -> char* {
        char* p = wsb + off;
        off += ra(bytes);
        return p;
    };

    u16* WpP = (u16*)alloc((size_t)MLP_ * FD_ * 2);
    u16* W1H = (u16*)alloc((size_t)HID_ * MLP_ * 2);
    u16* W2H = (u16*)alloc((size_t)HH_ * HID_ * 2);
    float* wts = (float*)alloc((size_t)NW_ * 4);

    const size_t fixed = off;
    int NB = 32;
    for (;;) {
        const size_t M = (size_t)NB * NW_;
        const size_t Mp = ((M + 127) / 128) * 128;
        const size_t need = ra(Mp * FD_ * 2) +        // featP
                            ra(Mp * 256 * 2) +        // projH
                            ra((Mp / 128) * 2 * 4);   // partial
        if (fixed + need <= ws_size || NB == 1) break;
        NB >>= 1;
    }
    const size_t Mmax  = (size_t)NB * NW_;
    const size_t MpMax = ((Mmax + 127) / 128) * 128;
    u16* featH = (u16*)alloc(MpMax * FD_ * 2);
    u16* projH = (u16*)alloc(MpMax * 256 * 2);
    float* partial = (float*)alloc((MpMax / 128) * 2 * 4);

    prep_kernel<<<dim3(177), dim3(256), 0, stream>>>(
        Wp, W1, W2, agg, WpP, W1H, W2H, wts);

    for (int b0 = 0; b0 < B_; b0 += NB) {
        const int nb = (B_ - b0 < NB) ? (B_ - b0) : NB;
        const int M = nb * NW_;
        const int Mp = ((M + 127) / 128) * 128;

        feat_kernel<<<dim3(NT_, 4, nb), dim3(256), 0, stream>>>(
            x + (size_t)b0 * C_ * T_, (u32*)featH);

        // proj = tanh(feat @ WpP^T + bp) * pi   (K=2112, BK=64)
        gemm64_kernel<<<dim3(Mp / 128), dim3(512), 0, stream>>>(
            featH, WpP, bp, PI_F, projH, M, FD_);

        // fused MLP tail: h1 + h2 + weighted reduce -> partials
        mlp_tail_kernel<<<dim3(Mp / 128), dim3(512), 0, stream>>>(
            projH, W1H, b1, W2H, b2, Wout, bout, wts, partial, M);

        finred_kernel<<<dim3(1), dim3(64), 0, stream>>>(
            partial, out + b0, nb, Mp / 128);
    }
}

// Round 20
// 119.310 us; speedup vs baseline: 1.0319x; 1.0319x over previous
//
#include <hip/hip_runtime.h>
#include <math.h>

#define B_   32
#define C_   32
#define T_   1024
#define NF_  33
#define F2_  66      // NF*2
#define FD_  2112    // C_*F2_
#define FDH_ 1056    // FD_/2 (u32)
#define NW_  961
#define MLP_ 256
#define HID_ 256
#define HH_  128
#define TN_  32
#define NT_  31      // ceil(961/32)

#define PI_F     3.14159265358979323846f
#define LN2_F    0.69314718055994530942f
#define L2E2_F   2.88539008177792681472f   // 2*log2(e)

typedef unsigned short u16;
typedef unsigned int   u32;
typedef __attribute__((ext_vector_type(8))) short bf16x8;
typedef __attribute__((ext_vector_type(4))) float f32x4;

__device__ __forceinline__ u16 f2bf(float f) {
    u32 u = __float_as_uint(f);
    u = u + 0x7FFFu + ((u >> 16) & 1u);   // RNE
    return (u16)(u >> 16);
}
// pack (lo, hi) -> u32{bf16(hi)<<16 | bf16(lo)}, RNE, single instruction
__device__ __forceinline__ u32 pk_bf16(float lo, float hi) {
    u32 r;
    asm("v_cvt_pk_bf16_f32 %0, %1, %2" : "=v"(r) : "v"(lo), "v"(hi));
    return r;
}
__device__ __forceinline__ void gload16(const void* g, void* l) {
    __builtin_amdgcn_global_load_lds(
        (const __attribute__((address_space(1))) void*)g,
        (__attribute__((address_space(3))) void*)l, 16, 0, 0);
}
__device__ __forceinline__ float ftanh(float x) {
    float z = __builtin_amdgcn_exp2f(x * L2E2_F);
    return 1.f - 2.f * __builtin_amdgcn_rcpf(z + 1.f);
}
__device__ __forceinline__ float flog1p(float x) {
    return __builtin_amdgcn_logf(1.f + x) * LN2_F;   // v_log_f32 is log2
}
// atan2(y,x)/pi, 4-term poly, max err ~3e-6 (pi units) -- << bf16 quantum
__device__ __forceinline__ float fatan2pi(float y, float x) {
    const float ay = fabsf(y), ax = fabsf(x);
    const float mn = fminf(ay, ax), mx = fmaxf(ay, ax);
    float t = mn * __builtin_amdgcn_rcpf(mx);
    t = (mx == 0.f) ? 0.f : t;
    const float s = t * t;
    float p = -0.027097f;
    p = fmaf(p, s,  0.057337f);
    p = fmaf(p, s, -0.105130f);
    p = fmaf(p, s,  0.318268f);
    p *= t;
    p = (ay > ax) ? 0.5f - p : p;
    p = (x < 0.f) ? 1.0f - p : p;
    return copysignf(p, y);
}

// ---------------------------------------------------------------------------
// prep: Wp -> bf16 with K-PERMUTATION matching feat's coalesced layout:
//   src k = c*66 + q (q=2f+p):  kp = (q<64) ? 64c+q : 2048 + 2c + (q-64)
// W1/W2 -> plain bf16 hi. block 176: softmax.
// ---------------------------------------------------------------------------
__global__ __launch_bounds__(256) void prep_kernel(
        const float* __restrict__ Wp, const float* __restrict__ W1,
        const float* __restrict__ W2, const float* __restrict__ agg,
        u16* __restrict__ WpP, u16* __restrict__ W1H, u16* __restrict__ W2H,
        float* __restrict__ wts) {
    const int blk = blockIdx.x;
    const int tid = threadIdx.x;
    if (blk < 128) {
        const int total = MLP_ * FD_;
        for (int i = blk * 256 + tid; i < total; i += 128 * 256) {
            const int n = i / FD_;
            const int k = i - n * FD_;
            const int c = k / F2_;
            const int q = k - c * F2_;
            const int kp = (q < 64) ? (c * 64 + q) : (2048 + 2 * c + (q - 64));
            WpP[(size_t)n * FD_ + kp] = f2bf(Wp[i]);
        }
    } else if (blk < 160) {
        const int total = HID_ * MLP_;
        for (int i = (blk - 128) * 256 + tid; i < total; i += 32 * 256)
            W1H[i] = f2bf(W1[i]);
    } else if (blk < 176) {
        const int total = HH_ * HID_;
        for (int i = (blk - 160) * 256 + tid; i < total; i += 16 * 256)
            W2H[i] = f2bf(W2[i]);
    } else {
        __shared__ float red[256];
        float mx = -INFINITY;
        for (int i = tid; i < NW_; i += 256) mx = fmaxf(mx, agg[i]);
        red[tid] = mx; __syncthreads();
        for (int s = 128; s > 0; s >>= 1) {
            if (tid < s) red[tid] = fmaxf(red[tid], red[tid + s]);
            __syncthreads();
        }
        mx = red[0]; __syncthreads();
        float sm = 0.f;
        for (int i = tid; i < NW_; i += 256) sm += expf(agg[i] - mx);
        red[tid] = sm; __syncthreads();
        for (int s = 128; s > 0; s >>= 1) {
            if (tid < s) red[tid] += red[tid + s];
            __syncthreads();
        }
        const float inv = 1.f / red[0];
        for (int i = tid; i < NW_; i += 256) wts[i] = expf(agg[i] - mx) * inv;
    }
}

// ---------------------------------------------------------------------------
// feat v5b: SLIDING DFT with basisT table (round-18, validated), basisT
// padding trimmed [64][68]->[64][66]: LDS = 20480B exactly -> 8 blocks/CU
// (was 7). Row-stride padding was dead (all lanes read the same k-row).
// Coalesced K-permuted store layout.
// ---------------------------------------------------------------------------
__global__ __launch_bounds__(256) void feat_kernel(const float* __restrict__ x,
                                                   u32* __restrict__ featP) {
    const int n0 = blockIdx.x * TN_;
    const int cg = blockIdx.y;
    const int bb = blockIdx.z;
    const int tid = threadIdx.x;
    const int tf = tid & 31;     // bin 0..31
    const int c8 = tid >> 5;     // channel-in-group 0..7
    const int c  = cg * 8 + c8;

    __shared__ float2 stab[64];          // 512 B
    __shared__ float xs[8][96];          // 3072 B
    __shared__ float basisT[64][66];     // 16896 B  (total 20480 = 8 blk/CU)

    if (tid < 64) {
        float s, cc;
        sincosf(-PI_F * (float)tid / 32.0f, &s, &cc);
        stab[tid] = make_float2(cc, s);
    }
    __syncthreads();
    for (int e = tid; e < 2048; e += 256) {
        const int f = e >> 6, k = e & 63;
        const float2 w = stab[(f * k) & 63];
        basisT[k][2 * f]     = w.x;
        basisT[k][2 * f + 1] = w.y;
    }
    if (tid < 192) {
        const int cs = tid / 24, q = tid % 24;
        const int t0 = n0 + q * 4;
        const float* xb = x + ((size_t)bb * C_ + cg * 8 + cs) * T_;
        float4 v;
        if (t0 + 3 < T_) {
            v = *(const float4*)(xb + t0);
        } else {
            v.x = (t0 + 0 < T_) ? xb[t0 + 0] : 0.f;
            v.y = (t0 + 1 < T_) ? xb[t0 + 1] : 0.f;
            v.z = (t0 + 2 < T_) ? xb[t0 + 2] : 0.f;
            v.w = 0.f;
        }
        *(float4*)&xs[cs][q * 4] = v;
    }
    __syncthreads();

    const size_t rowb = (size_t)bb * NW_;

    // phase 1: bins 0..31, sliding across 32 windows
    {
        float re = 0.f, im = 0.f;
#pragma unroll
        for (int k = 0; k < 64; ++k) {
            const float xv = xs[c8][k];
            const float2 w = *(const float2*)&basisT[k][2 * tf];
            re = fmaf(xv, w.x, re);
            im = fmaf(xv, w.y, im);
        }
        const float2 st = stab[tf];
        const float cx = st.x, sx = -st.y;

        u32* fp = featP + (rowb + n0) * FDH_ + (c << 5) + tf;
        const int nw = (NW_ - n0 < TN_) ? (NW_ - n0) : TN_;
        for (int j = 0; j < nw; ++j) {
            const float r   = __builtin_amdgcn_sqrtf(fmaf(re, re, im * im));
            const float mag = flog1p(r);
            const float ph  = fatan2pi(im, re);
            *fp = pk_bf16(mag, ph);
            fp += FDH_;
            const float tre = re - xs[c8][j] + xs[c8][j + 64];
            re = tre * cx - im * sx;
            im = tre * sx + im * cx;
        }
    }

    // phase 2: Nyquist bin -> tail block [row][1024 + c]
    {
        const int j   = tid & 31;
        const int c8n = tid >> 5;
        const int gn  = n0 + j;
        if (gn < NW_) {
            float s = 0.f;
#pragma unroll
            for (int k = 0; k < 32; ++k)
                s += xs[c8n][j + 2 * k] - xs[c8n][j + 2 * k + 1];
            const float a = flog1p(fabsf(s));
            const float p = (__float_as_uint(s) >> 31) ? 1.0f : 0.0f;
            featP[(rowb + gn) * FDH_ + 1024 + cg * 8 + c8n] = pk_bf16(a, p);
        }
    }
}

// ---------------------------------------------------------------------------
// gemm64 (round-17, validated): proj GEMM, BK=64, BM=128 x BN=256, 512 thr.
// 3-buffer depth-2 counted-vmcnt, STEPB=48KB, LDS=144KB, 33 K-steps.
// ---------------------------------------------------------------------------
__global__ __launch_bounds__(512, 1) void gemm64_kernel(
        const u16* __restrict__ A, const u16* __restrict__ BH,
        const float* __restrict__ bias, float scale,
        u16* __restrict__ outH, int Mvalid, int Kd) {
    constexpr int STEPB = 16384 + 32768;    // A 16K | B 32K
    __shared__ char lds[3 * STEPB];         // 147456

    const int bm = blockIdx.x;
    const int tid = threadIdx.x;
    const int lane = tid & 63, w = tid >> 6;
    const int wr = w >> 2, wc = w & 3;      // 2 x 4 waves of 64x64
    const int m0 = bm * 128;

    f32x4 acc[4][4];
#pragma unroll
    for (int i = 0; i < 4; ++i)
#pragma unroll
        for (int j = 0; j < 4; ++j) acc[i][j] = (f32x4){0.f, 0.f, 0.f, 0.f};

    const size_t rs = (size_t)Kd * 2;
    const char* gA = (const char*)A + (size_t)m0 * rs;
    const char* gB = (const char*)BH;

    auto st1 = [&](const char* g, char* l, int idx) {
        const int row = idx >> 3;
        const int kc  = (idx & 7) ^ ((row >> 1) & 7);
        gload16(g + (size_t)row * rs + (size_t)(kc << 4), l + idx * 16);
    };
    auto stage = [&](int buf, int t) {
        const size_t k0b = (size_t)t << 7;          // t*128 bytes
        char* lb = lds + buf * STEPB;
        st1(gA + k0b, lb, tid);
        st1(gA + k0b, lb, tid + 512);
        st1(gB + k0b, lb + 16384, tid);
        st1(gB + k0b, lb + 16384, tid + 512);
        st1(gB + k0b, lb + 16384, tid + 1024);
        st1(gB + k0b, lb + 16384, tid + 1536);
    };

    const int q   = lane >> 4;
    const int ra_ = wr * 64 + (lane & 15);
    const int rb_ = wc * 64 + (lane & 15);
    const int s3a = (ra_ >> 1) & 7;
    const int s3b = (rb_ >> 1) & 7;
    const int ab0 = ra_ * 128 + (((0 * 4 + q) ^ s3a) << 4);
    const int ab1 = ra_ * 128 + (((1 * 4 + q) ^ s3a) << 4);
    const int bb0 = rb_ * 128 + (((0 * 4 + q) ^ s3b) << 4);
    const int bb1 = rb_ * 128 + (((1 * 4 + q) ^ s3b) << 4);

    const int nt = Kd >> 6;   // 33

    stage(0, 0);
    stage(1, 1);

    int cur = 0;
    for (int t = 0; t < nt; ++t) {
        if (t + 1 < nt)
            asm volatile("s_waitcnt vmcnt(6)" ::: "memory");
        else
            asm volatile("s_waitcnt vmcnt(0)" ::: "memory");
        __builtin_amdgcn_sched_barrier(0);
        __builtin_amdgcn_s_barrier();
        asm volatile("" ::: "memory");

        int pf = cur + 2; if (pf >= 3) pf -= 3;
        if (t + 2 < nt) stage(pf, t + 2);

        const char* lb = lds + cur * STEPB;
        bf16x8 a0[4], a1[4], b0[4], b1[4];
#pragma unroll
        for (int f = 0; f < 4; ++f) {
            a0[f] = *(const bf16x8*)(lb + ab0 + f * 2048);
            a1[f] = *(const bf16x8*)(lb + ab1 + f * 2048);
            b0[f] = *(const bf16x8*)(lb + 16384 + bb0 + f * 2048);
            b1[f] = *(const bf16x8*)(lb + 16384 + bb1 + f * 2048);
        }
        __builtin_amdgcn_s_setprio(1);
#pragma unroll
        for (int fm = 0; fm < 4; ++fm)
#pragma unroll
            for (int fn = 0; fn < 4; ++fn)
                acc[fm][fn] = __builtin_amdgcn_mfma_f32_16x16x32_bf16(a0[fm], b0[fn], acc[fm][fn], 0, 0, 0);
#pragma unroll
        for (int fm = 0; fm < 4; ++fm)
#pragma unroll
            for (int fn = 0; fn < 4; ++fn)
                acc[fm][fn] = __builtin_amdgcn_mfma_f32_16x16x32_bf16(a1[fm], b1[fn], acc[fm][fn], 0, 0, 0);
        __builtin_amdgcn_s_setprio(0);
        ++cur; if (cur >= 3) cur -= 3;
    }

    float bv[4];
#pragma unroll
    for (int fn = 0; fn < 4; ++fn) bv[fn] = bias[wc * 64 + fn * 16 + (lane & 15)];
#pragma unroll
    for (int fm = 0; fm < 4; ++fm) {
        const int rbase = m0 + wr * 64 + fm * 16 + (lane >> 4) * 4;
#pragma unroll
        for (int fn = 0; fn < 4; ++fn) {
            const int col = wc * 64 + fn * 16 + (lane & 15);
#pragma unroll
            for (int r = 0; r < 4; ++r) {
                const int row = rbase + r;
                if (row < Mvalid) {
                    const float v = ftanh(acc[fm][fn][r] + bv[fn]) * scale;
                    outH[(size_t)row * 256 + col] = f2bf(v);
                }
            }
        }
    }
}

// ---------------------------------------------------------------------------
// mlp_tail: FUSED h1 GEMM + h2 GEMM + weighted reduction (round-16, proven).
// ---------------------------------------------------------------------------
__global__ __launch_bounds__(512, 1) void mlp_tail_kernel(
        const u16* __restrict__ A, const u16* __restrict__ W1Hp,
        const float* __restrict__ b1, const u16* __restrict__ W2Hp,
        const float* __restrict__ b2, const float* __restrict__ Wout,
        const float* __restrict__ bout, const float* __restrict__ wts,
        float* __restrict__ partial, int Mvalid) {
    constexpr int STEPB = 8192 + 16384;     // phase-1 step: A 8K | B 16K
    constexpr int OFFX  = 3 * STEPB;        // 73728
    __shared__ char lds[OFFX + 65536];      // 139264

    const int bm = blockIdx.x;
    const int tid = threadIdx.x;
    const int lane = tid & 63, w = tid >> 6;
    const int m0 = bm * 128;
    const size_t rs = 512;                  // K=256 rows, bytes

    // ================= phase 1: h1 = tanh(proj @ W1^T + b1) =================
    {
        const int wr = w >> 2, wc = w & 3;
        f32x4 acc[4][4];
#pragma unroll
        for (int i = 0; i < 4; ++i)
#pragma unroll
            for (int j = 0; j < 4; ++j) acc[i][j] = (f32x4){0.f, 0.f, 0.f, 0.f};

        const char* gA = (const char*)A + (size_t)m0 * rs;
        const char* gB = (const char*)W1Hp;

        auto st1 = [&](const char* g, char* l, int idx) {
            const int row = idx >> 2;
            const int kc  = (idx & 3) ^ ((row >> 1) & 3);
            gload16(g + (size_t)row * rs + (size_t)(kc << 4), l + idx * 16);
        };
        auto stage = [&](int buf, int t) {
            const size_t k0b = (size_t)t << 6;
            char* lb = lds + buf * STEPB;
            st1(gA + k0b, lb, tid);
            st1(gB + k0b, lb + 8192, tid);
            st1(gB + k0b, lb + 8192, tid + 512);
        };

        const int ra_ = wr * 64 + (lane & 15);
        const int rb_ = wc * 64 + (lane & 15);
        const int q   = lane >> 4;
        const int abase = ra_ * 64 + ((q ^ ((ra_ >> 1) & 3)) << 4);
        const int bbase = rb_ * 64 + ((q ^ ((rb_ >> 1) & 3)) << 4);

        stage(0, 0);
        stage(1, 1);

        int cur = 0;
        for (int t = 0; t < 8; ++t) {
            if (t + 1 < 8)
                asm volatile("s_waitcnt vmcnt(3)" ::: "memory");
            else
                asm volatile("s_waitcnt vmcnt(0)" ::: "memory");
            __builtin_amdgcn_sched_barrier(0);
            __builtin_amdgcn_s_barrier();
            asm volatile("" ::: "memory");

            int pf = cur + 2; if (pf >= 3) pf -= 3;
            if (t + 2 < 8) stage(pf, t + 2);

            const char* lb = lds + cur * STEPB;
            bf16x8 a4[4], b4[4];
#pragma unroll
            for (int f = 0; f < 4; ++f) {
                a4[f] = *(const bf16x8*)(lb + abase + f * 1024);
                b4[f] = *(const bf16x8*)(lb + 8192 + bbase + f * 1024);
            }
            __builtin_amdgcn_s_setprio(1);
#pragma unroll
            for (int fm = 0; fm < 4; ++fm)
#pragma unroll
                for (int fn = 0; fn < 4; ++fn)
                    acc[fm][fn] = __builtin_amdgcn_mfma_f32_16x16x32_bf16(a4[fm], b4[fn], acc[fm][fn], 0, 0, 0);
            __builtin_amdgcn_s_setprio(0);
            ++cur; if (cur >= 3) cur -= 3;
        }

        float bv[4];
#pragma unroll
        for (int fn = 0; fn < 4; ++fn) bv[fn] = b1[wc * 64 + fn * 16 + (lane & 15)];
#pragma unroll
        for (int fm = 0; fm < 4; ++fm) {
#pragma unroll
            for (int fn = 0; fn < 4; ++fn) {
                const int col = wc * 64 + fn * 16 + (lane & 15);
                const int cpart = ((col >> 5) << 6) + ((col & 7) * 2);
                const int kc = (col >> 3) & 3;
#pragma unroll
                for (int r = 0; r < 4; ++r) {
                    const int row = wr * 64 + fm * 16 + (lane >> 4) * 4 + r;
                    const float v = ftanh(acc[fm][fn][r] + bv[fn]);
                    const int byt = row * 512 + cpart + ((kc ^ ((row >> 1) & 3)) << 4);
                    *(u16*)(lds + OFFX + byt) = f2bf(v);
                }
            }
        }
    }
    __syncthreads();   // full drain: X visible to all waves

    // ================= phase 2: h2 = tanh(h1 @ W2^T + b2) =================
    f32x4 acc2[4][4];
#pragma unroll
    for (int i = 0; i < 4; ++i)
#pragma unroll
        for (int j = 0; j < 4; ++j) acc2[i][j] = (f32x4){0.f, 0.f, 0.f, 0.f};

    const int wr2 = (w >> 1) & 1, wc2 = w & 1;   // meaningful for w<4
    {
        const char* gB2 = (const char*)W2Hp;
        auto st2 = [&](int buf, int t) {
            const size_t k0b = (size_t)t << 6;
            const int row = tid >> 2;                 // 0..127
            const int kc  = (tid & 3) ^ ((row >> 1) & 3);
            gload16(gB2 + (size_t)row * rs + k0b + (size_t)(kc << 4),
                    lds + buf * STEPB + tid * 16);
        };
        st2(0, 0);
        st2(1, 1);

        const int q = lane >> 4;
        const int rb = wc2 * 64 + (lane & 15);
        const int bbase = rb * 64 + ((q ^ ((rb >> 1) & 3)) << 4);
        const int ra = wr2 * 64 + (lane & 15);
        const int abase = ra * 512 + ((q ^ ((ra >> 1) & 3)) << 4);

        int cur = 0;
        for (int t = 0; t < 8; ++t) {
            if (t + 1 < 8)
                asm volatile("s_waitcnt vmcnt(1)" ::: "memory");
            else
                asm volatile("s_waitcnt vmcnt(0)" ::: "memory");
            __builtin_amdgcn_sched_barrier(0);
            __builtin_amdgcn_s_barrier();
            asm volatile("" ::: "memory");

            int pf = cur + 2; if (pf >= 3) pf -= 3;
            if (t + 2 < 8) st2(pf, t + 2);

            if (w < 4) {
                const char* lb = lds + cur * STEPB;
                bf16x8 a4[4], b4[4];
#pragma unroll
                for (int f = 0; f < 4; ++f) {
                    a4[f] = *(const bf16x8*)(lds + OFFX + abase + f * 8192 + t * 64);
                    b4[f] = *(const bf16x8*)(lb + bbase + f * 1024);
                }
                __builtin_amdgcn_s_setprio(1);
#pragma unroll
                for (int fm = 0; fm < 4; ++fm)
#pragma unroll
                    for (int fn = 0; fn < 4; ++fn)
                        acc2[fm][fn] = __builtin_amdgcn_mfma_f32_16x16x32_bf16(a4[fm], b4[fn], acc2[fm][fn], 0, 0, 0);
                __builtin_amdgcn_s_setprio(0);
            }
            ++cur; if (cur >= 3) cur -= 3;
        }
    }

    // ================= phase 3: weighted reduction =================
    __syncthreads();
    float* rsum = (float*)lds;               // [128][2]
    float* red  = (float*)(lds + 1024);      // [256]

    if (w < 4) {
        float bv[4], wv[4];
#pragma unroll
        for (int fn = 0; fn < 4; ++fn) {
            const int col = wc2 * 64 + fn * 16 + (lane & 15);
            bv[fn] = b2[col];
            wv[fn] = Wout[col];
        }
#pragma unroll
        for (int fm = 0; fm < 4; ++fm) {
#pragma unroll
            for (int r = 0; r < 4; ++r) {
                float c = 0.f;
#pragma unroll
                for (int fn = 0; fn < 4; ++fn)
                    c += ftanh(acc2[fm][fn][r] + bv[fn]) * wv[fn];
                c += __shfl_xor(c, 1);
                c += __shfl_xor(c, 2);
                c += __shfl_xor(c, 4);
                c += __shfl_xor(c, 8);
                if ((lane & 15) == 0)
                    rsum[(wr2 * 64 + fm * 16 + (lane >> 4) * 4 + r) * 2 + wc2] = c;
            }
        }
    }
    __syncthreads();

    const float bO = bout[0];
    float val = 0.f;
    int rowb = -1;
    if (tid < 128) {
        const int gr = m0 + tid;
        if (gr < Mvalid) {
            const float dot = rsum[tid * 2] + rsum[tid * 2 + 1] + bO;
            rowb = gr / NW_;
            val = dot * wts[gr - rowb * NW_];
        }
    }
    __syncthreads();

    const int bFirst = m0 / NW_;
    if (tid < 256) red[tid] = (tid < 128 && rowb == bFirst) ? val : 0.f;
    __syncthreads();
    for (int s = 128; s > 0; s >>= 1) {
        if (tid < s) red[tid] += red[tid + s];
        __syncthreads();
    }
    if (tid == 0) partial[bm * 2] = red[0];
    __syncthreads();
    if (tid < 256) red[tid] = (tid < 128 && rowb == bFirst + 1) ? val : 0.f;
    __syncthreads();
    for (int s = 128; s > 0; s >>= 1) {
        if (tid < s) red[tid] += red[tid + s];
        __syncthreads();
    }
    if (tid == 0) partial[bm * 2 + 1] = red[0];
}

// ---------------------------------------------------------------------------
// finred: out[b0+b] = fixed-order sum of partial slots spanning batch b.
// ---------------------------------------------------------------------------
__global__ __launch_bounds__(64) void finred_kernel(const float* __restrict__ partial,
                                                    float* __restrict__ out,
                                                    int nbat, int nblocks) {
    const int b = threadIdx.x;
    if (b >= nbat) return;
    int lo = (b * NW_) / 128;
    int hi = ((b + 1) * NW_ - 1) / 128;
    if (hi > nblocks - 1) hi = nblocks - 1;
    float s = 0.f;
    for (int bm = lo; bm <= hi; ++bm) {
        const int slot = ((bm * 128) / NW_ == b) ? 0 : 1;
        s += partial[bm * 2 + slot];
    }
    out[b] = s;
}

// ---------------------------------------------------------------------------
extern "C" void kernel_launch(void* const* d_in, const int* in_sizes, int n_in,
                              void* d_out, int out_size, void* d_ws, size_t ws_size,
                              hipStream_t stream) {
    const float* x    = (const float*)d_in[0];
    const float* Wp   = (const float*)d_in[1];
    const float* bp   = (const float*)d_in[2];
    const float* W1   = (const float*)d_in[3];
    const float* b1   = (const float*)d_in[4];
    const float* W2   = (const float*)d_in[5];
    const float* b2   = (const float*)d_in[6];
    const float* Wout = (const float*)d_in[7];
    const float* bout = (const float*)d_in[8];
    const float* agg  = (const float*)d_in[9];
    float* out = (float*)d_out;

    char* wsb = (char*)d_ws;
    size_t off = 0;
    auto ra = [](size_t b) { return (b + 255) & ~(size_t)255; };
    auto alloc = [&](size_t bytes) -> char* {
        char* p = wsb + off;
        off += ra(bytes);
        return p;
    };

    u16* WpP = (u16*)alloc((size_t)MLP_ * FD_ * 2);
    u16* W1H = (u16*)alloc((size_t)HID_ * MLP_ * 2);
    u16* W2H = (u16*)alloc((size_t)HH_ * HID_ * 2);
    float* wts = (float*)alloc((size_t)NW_ * 4);

    const size_t fixed = off;
    int NB = 32;
    for (;;) {
        const size_t M = (size_t)NB * NW_;
        const size_t Mp = ((M + 127) / 128) * 128;
        const size_t need = ra(Mp * FD_ * 2) +        // featP
                            ra(Mp * 256 * 2) +        // projH
                            ra((Mp / 128) * 2 * 4);   // partial
        if (fixed + need <= ws_size || NB == 1) break;
        NB >>= 1;
    }
    const size_t Mmax  = (size_t)NB * NW_;
    const size_t MpMax = ((Mmax + 127) / 128) * 128;
    u16* featH = (u16*)alloc(MpMax * FD_ * 2);
    u16* projH = (u16*)alloc(MpMax * 256 * 2);
    float* partial = (float*)alloc((MpMax / 128) * 2 * 4);

    prep_kernel<<<dim3(177), dim3(256), 0, stream>>>(
        Wp, W1, W2, agg, WpP, W1H, W2H, wts);

    for (int b0 = 0; b0 < B_; b0 += NB) {
        const int nb = (B_ - b0 < NB) ? (B_ - b0) : NB;
        const int M = nb * NW_;
        const int Mp = ((M + 127) / 128) * 128;

        feat_kernel<<<dim3(NT_, 4, nb), dim3(256), 0, stream>>>(
            x + (size_t)b0 * C_ * T_, (u32*)featH);

        // proj = tanh(feat @ WpP^T + bp) * pi   (K=2112, BK=64)
        gemm64_kernel<<<dim3(Mp / 128), dim3(512), 0, stream>>>(
            featH, WpP, bp, PI_F, projH, M, FD_);

        // fused MLP tail: h1 + h2 + weighted reduce -> partials
        mlp_tail_kernel<<<dim3(Mp / 128), dim3(512), 0, stream>>>(
            projH, W1H, b1, W2H, b2, Wout, bout, wts, partial, M);

        finred_kernel<<<dim3(1), dim3(64), 0, stream>>>(
            partial, out + b0, nb, Mp / 128);
    }
}

// Round 21
// 110.993 us; speedup vs baseline: 1.1092x; 1.0749x over previous
//
#include <hip/hip_runtime.h>
#include <math.h>

#define B_   32
#define C_   32
#define T_   1024
#define NF_  33
#define F2_  66      // NF*2
#define FD_  2112    // C_*F2_
#define FDH_ 1056    // FD_/2 (u32)
#define NW_  961
#define MLP_ 256
#define HID_ 256
#define HH_  128
#define TN_  64      // windows per feat tile
#define NT_  16      // ceil(961/64)

#define PI_F     3.14159265358979323846f
#define LN2_F    0.69314718055994530942f
#define L2E2_F   2.88539008177792681472f   // 2*log2(e)

typedef unsigned short u16;
typedef unsigned int   u32;
typedef __attribute__((ext_vector_type(8))) short bf16x8;
typedef __attribute__((ext_vector_type(4))) float f32x4;

__device__ __forceinline__ u16 f2bf(float f) {
    u32 u = __float_as_uint(f);
    u = u + 0x7FFFu + ((u >> 16) & 1u);   // RNE
    return (u16)(u >> 16);
}
// pack (lo, hi) -> u32{bf16(hi)<<16 | bf16(lo)}, RNE, single instruction
__device__ __forceinline__ u32 pk_bf16(float lo, float hi) {
    u32 r;
    asm("v_cvt_pk_bf16_f32 %0, %1, %2" : "=v"(r) : "v"(lo), "v"(hi));
    return r;
}
__device__ __forceinline__ void gload16(const void* g, void* l) {
    __builtin_amdgcn_global_load_lds(
        (const __attribute__((address_space(1))) void*)g,
        (__attribute__((address_space(3))) void*)l, 16, 0, 0);
}
__device__ __forceinline__ float ftanh(float x) {
    float z = __builtin_amdgcn_exp2f(x * L2E2_F);
    return 1.f - 2.f * __builtin_amdgcn_rcpf(z + 1.f);
}
__device__ __forceinline__ float flog1p(float x) {
    return __builtin_amdgcn_logf(1.f + x) * LN2_F;   // v_log_f32 is log2
}
// atan2(y,x)/pi, 4-term poly, max err ~3e-6 (pi units) -- << bf16 quantum
__device__ __forceinline__ float fatan2pi(float y, float x) {
    const float ay = fabsf(y), ax = fabsf(x);
    const float mn = fminf(ay, ax), mx = fmaxf(ay, ax);
    float t = mn * __builtin_amdgcn_rcpf(mx);
    t = (mx == 0.f) ? 0.f : t;
    const float s = t * t;
    float p = -0.027097f;
    p = fmaf(p, s,  0.057337f);
    p = fmaf(p, s, -0.105130f);
    p = fmaf(p, s,  0.318268f);
    p *= t;
    p = (ay > ax) ? 0.5f - p : p;
    p = (x < 0.f) ? 1.0f - p : p;
    return copysignf(p, y);
}

// ---------------------------------------------------------------------------
// prepfeat: MERGED weight-conversion/softmax + sliding-DFT features.
// blocks [0,128): Wp -> K-permuted bf16 (kp = (q<64) ? 64c+q : 2048+2c+(q-64)).
// [128,160): W1 -> bf16. [160,176): W2 -> bf16. 176: softmax(agg).
// [177, 177+64*nb): feat, TN=64 windows per tile (init DFT amortized 2x).
// feat layout (round-18, validated): u32 idx row*1056 + c*32 + f;
// Nyquist at row*1056 + 1024 + c. 128B-aligned wave stores.
// ---------------------------------------------------------------------------
__global__ __launch_bounds__(256) void prepfeat_kernel(
        const float* __restrict__ x,
        const float* __restrict__ Wp, const float* __restrict__ W1,
        const float* __restrict__ W2, const float* __restrict__ agg,
        u16* __restrict__ WpP, u16* __restrict__ W1H, u16* __restrict__ W2H,
        float* __restrict__ wts, u32* __restrict__ featP) {
    const int blk = blockIdx.x;
    const int tid = threadIdx.x;

    if (blk < 177) {
        if (blk < 128) {
            const int total = MLP_ * FD_;
            for (int i = blk * 256 + tid; i < total; i += 128 * 256) {
                const int n = i / FD_;
                const int k = i - n * FD_;
                const int c = k / F2_;
                const int q = k - c * F2_;
                const int kp = (q < 64) ? (c * 64 + q) : (2048 + 2 * c + (q - 64));
                WpP[(size_t)n * FD_ + kp] = f2bf(Wp[i]);
            }
        } else if (blk < 160) {
            const int total = HID_ * MLP_;
            for (int i = (blk - 128) * 256 + tid; i < total; i += 32 * 256)
                W1H[i] = f2bf(W1[i]);
        } else if (blk < 176) {
            const int total = HH_ * HID_;
            for (int i = (blk - 160) * 256 + tid; i < total; i += 16 * 256)
                W2H[i] = f2bf(W2[i]);
        } else {
            __shared__ float red[256];
            float mx = -INFINITY;
            for (int i = tid; i < NW_; i += 256) mx = fmaxf(mx, agg[i]);
            red[tid] = mx; __syncthreads();
            for (int s = 128; s > 0; s >>= 1) {
                if (tid < s) red[tid] = fmaxf(red[tid], red[tid + s]);
                __syncthreads();
            }
            mx = red[0]; __syncthreads();
            float sm = 0.f;
            for (int i = tid; i < NW_; i += 256) sm += expf(agg[i] - mx);
            red[tid] = sm; __syncthreads();
            for (int s = 128; s > 0; s >>= 1) {
                if (tid < s) red[tid] += red[tid + s];
                __syncthreads();
            }
            const float inv = 1.f / red[0];
            for (int i = tid; i < NW_; i += 256) wts[i] = expf(agg[i] - mx) * inv;
        }
        return;
    }

    // ---- feat part: TN=64 windows per tile ----
    const int fb  = blk - 177;
    const int bb  = fb >> 6;            // batch
    const int r2  = fb & 63;
    const int cg  = r2 >> 4;            // channel group (8 ch)
    const int n0  = (r2 & 15) * TN_;    // window tile start
    const int tf  = tid & 31;           // bin 0..31
    const int c8  = tid >> 5;           // channel-in-group 0..7
    const int c   = cg * 8 + c8;

    __shared__ float2 stab[64];          // 512 B
    __shared__ float xs[8][128];         // 4096 B
    __shared__ float basisT[64][66];     // 16896 B  (total 21504)

    if (tid < 64) {
        float s, cc;
        sincosf(-PI_F * (float)tid / 32.0f, &s, &cc);
        stab[tid] = make_float2(cc, s);
    }
    __syncthreads();
    for (int e = tid; e < 2048; e += 256) {
        const int f = e >> 6, k = e & 63;
        const float2 w = stab[(f * k) & 63];
        basisT[k][2 * f]     = w.x;
        basisT[k][2 * f + 1] = w.y;
    }
    {   // xs fill: 8 ch x 128 samples (one float4 per thread)
        const int cs = tid >> 5, q = tid & 31;
        const int t0 = n0 + q * 4;
        const float* xb = x + ((size_t)bb * C_ + cg * 8 + cs) * T_;
        float4 v = {0.f, 0.f, 0.f, 0.f};
        if (t0 + 3 < T_) {
            v = *(const float4*)(xb + t0);
        } else {
            if (t0 + 0 < T_) v.x = xb[t0 + 0];
            if (t0 + 1 < T_) v.y = xb[t0 + 1];
            if (t0 + 2 < T_) v.z = xb[t0 + 2];
        }
        *(float4*)&xs[cs][q * 4] = v;
    }
    __syncthreads();

    const size_t rowb = (size_t)bb * NW_;

    // phase 1: bins 0..31, sliding across up to 64 windows
    {
        float re = 0.f, im = 0.f;
#pragma unroll
        for (int k = 0; k < 64; ++k) {
            const float xv = xs[c8][k];
            const float2 w = *(const float2*)&basisT[k][2 * tf];
            re = fmaf(xv, w.x, re);
            im = fmaf(xv, w.y, im);
        }
        const float2 st = stab[tf];
        const float cx = st.x, sx = -st.y;

        u32* fp = featP + (rowb + n0) * FDH_ + (c << 5) + tf;
        const int nw = (NW_ - n0 < TN_) ? (NW_ - n0) : TN_;
        for (int j = 0; j < nw; ++j) {
            const float r   = __builtin_amdgcn_sqrtf(fmaf(re, re, im * im));
            const float mag = flog1p(r);
            const float ph  = fatan2pi(im, re);
            *fp = pk_bf16(mag, ph);
            fp += FDH_;
            const float tre = re - xs[c8][j] + xs[c8][j + 64];
            re = tre * cx - im * sx;
            im = tre * sx + im * cx;
        }
    }

    // phase 2: Nyquist bin -> tail block [row][1024 + c]; 2 windows/thread
    {
        const int c8n = tid >> 5;
#pragma unroll
        for (int half = 0; half < 2; ++half) {
            const int j  = (tid & 31) + half * 32;
            const int gn = n0 + j;
            if (gn < NW_) {
                float s = 0.f;
#pragma unroll
                for (int k = 0; k < 32; ++k)
                    s += xs[c8n][j + 2 * k] - xs[c8n][j + 2 * k + 1];
                const float a = flog1p(fabsf(s));
                const float p = (__float_as_uint(s) >> 31) ? 1.0f : 0.0f;
                featP[(rowb + gn) * FDH_ + 1024 + cg * 8 + c8n] = pk_bf16(a, p);
            }
        }
    }
}

// ---------------------------------------------------------------------------
// gemm64 (round-17, validated): proj GEMM, BK=64, BM=128 x BN=256, 512 thr.
// 3-buffer depth-2 counted-vmcnt, STEPB=48KB, LDS=144KB, 33 K-steps.
// ---------------------------------------------------------------------------
__global__ __launch_bounds__(512, 1) void gemm64_kernel(
        const u16* __restrict__ A, const u16* __restrict__ BH,
        const float* __restrict__ bias, float scale,
        u16* __restrict__ outH, int Mvalid, int Kd) {
    constexpr int STEPB = 16384 + 32768;    // A 16K | B 32K
    __shared__ char lds[3 * STEPB];         // 147456

    const int bm = blockIdx.x;
    const int tid = threadIdx.x;
    const int lane = tid & 63, w = tid >> 6;
    const int wr = w >> 2, wc = w & 3;      // 2 x 4 waves of 64x64
    const int m0 = bm * 128;

    f32x4 acc[4][4];
#pragma unroll
    for (int i = 0; i < 4; ++i)
#pragma unroll
        for (int j = 0; j < 4; ++j) acc[i][j] = (f32x4){0.f, 0.f, 0.f, 0.f};

    const size_t rs = (size_t)Kd * 2;
    const char* gA = (const char*)A + (size_t)m0 * rs;
    const char* gB = (const char*)BH;

    auto st1 = [&](const char* g, char* l, int idx) {
        const int row = idx >> 3;
        const int kc  = (idx & 7) ^ ((row >> 1) & 7);
        gload16(g + (size_t)row * rs + (size_t)(kc << 4), l + idx * 16);
    };
    auto stage = [&](int buf, int t) {
        const size_t k0b = (size_t)t << 7;          // t*128 bytes
        char* lb = lds + buf * STEPB;
        st1(gA + k0b, lb, tid);
        st1(gA + k0b, lb, tid + 512);
        st1(gB + k0b, lb + 16384, tid);
        st1(gB + k0b, lb + 16384, tid + 512);
        st1(gB + k0b, lb + 16384, tid + 1024);
        st1(gB + k0b, lb + 16384, tid + 1536);
    };

    const int q   = lane >> 4;
    const int ra_ = wr * 64 + (lane & 15);
    const int rb_ = wc * 64 + (lane & 15);
    const int s3a = (ra_ >> 1) & 7;
    const int s3b = (rb_ >> 1) & 7;
    const int ab0 = ra_ * 128 + (((0 * 4 + q) ^ s3a) << 4);
    const int ab1 = ra_ * 128 + (((1 * 4 + q) ^ s3a) << 4);
    const int bb0 = rb_ * 128 + (((0 * 4 + q) ^ s3b) << 4);
    const int bb1 = rb_ * 128 + (((1 * 4 + q) ^ s3b) << 4);

    const int nt = Kd >> 6;   // 33

    stage(0, 0);
    stage(1, 1);

    int cur = 0;
    for (int t = 0; t < nt; ++t) {
        if (t + 1 < nt)
            asm volatile("s_waitcnt vmcnt(6)" ::: "memory");
        else
            asm volatile("s_waitcnt vmcnt(0)" ::: "memory");
        __builtin_amdgcn_sched_barrier(0);
        __builtin_amdgcn_s_barrier();
        asm volatile("" ::: "memory");

        int pf = cur + 2; if (pf >= 3) pf -= 3;
        if (t + 2 < nt) stage(pf, t + 2);

        const char* lb = lds + cur * STEPB;
        bf16x8 a0[4], a1[4], b0[4], b1[4];
#pragma unroll
        for (int f = 0; f < 4; ++f) {
            a0[f] = *(const bf16x8*)(lb + ab0 + f * 2048);
            a1[f] = *(const bf16x8*)(lb + ab1 + f * 2048);
            b0[f] = *(const bf16x8*)(lb + 16384 + bb0 + f * 2048);
            b1[f] = *(const bf16x8*)(lb + 16384 + bb1 + f * 2048);
        }
        __builtin_amdgcn_s_setprio(1);
#pragma unroll
        for (int fm = 0; fm < 4; ++fm)
#pragma unroll
            for (int fn = 0; fn < 4; ++fn)
                acc[fm][fn] = __builtin_amdgcn_mfma_f32_16x16x32_bf16(a0[fm], b0[fn], acc[fm][fn], 0, 0, 0);
#pragma unroll
        for (int fm = 0; fm < 4; ++fm)
#pragma unroll
            for (int fn = 0; fn < 4; ++fn)
                acc[fm][fn] = __builtin_amdgcn_mfma_f32_16x16x32_bf16(a1[fm], b1[fn], acc[fm][fn], 0, 0, 0);
        __builtin_amdgcn_s_setprio(0);
        ++cur; if (cur >= 3) cur -= 3;
    }

    float bv[4];
#pragma unroll
    for (int fn = 0; fn < 4; ++fn) bv[fn] = bias[wc * 64 + fn * 16 + (lane & 15)];
#pragma unroll
    for (int fm = 0; fm < 4; ++fm) {
        const int rbase = m0 + wr * 64 + fm * 16 + (lane >> 4) * 4;
#pragma unroll
        for (int fn = 0; fn < 4; ++fn) {
            const int col = wc * 64 + fn * 16 + (lane & 15);
#pragma unroll
            for (int r = 0; r < 4; ++r) {
                const int row = rbase + r;
                if (row < Mvalid) {
                    const float v = ftanh(acc[fm][fn][r] + bv[fn]) * scale;
                    outH[(size_t)row * 256 + col] = f2bf(v);
                }
            }
        }
    }
}

// ---------------------------------------------------------------------------
// mlp_tail: FUSED h1 GEMM + h2 GEMM + weighted reduction (round-16, proven).
// ---------------------------------------------------------------------------
__global__ __launch_bounds__(512, 1) void mlp_tail_kernel(
        const u16* __restrict__ A, const u16* __restrict__ W1Hp,
        const float* __restrict__ b1, const u16* __restrict__ W2Hp,
        const float* __restrict__ b2, const float* __restrict__ Wout,
        const float* __restrict__ bout, const float* __restrict__ wts,
        float* __restrict__ partial, int Mvalid) {
    constexpr int STEPB = 8192 + 16384;     // phase-1 step: A 8K | B 16K
    constexpr int OFFX  = 3 * STEPB;        // 73728
    __shared__ char lds[OFFX + 65536];      // 139264

    const int bm = blockIdx.x;
    const int tid = threadIdx.x;
    const int lane = tid & 63, w = tid >> 6;
    const int m0 = bm * 128;
    const size_t rs = 512;                  // K=256 rows, bytes

    // ================= phase 1: h1 = tanh(proj @ W1^T + b1) =================
    {
        const int wr = w >> 2, wc = w & 3;
        f32x4 acc[4][4];
#pragma unroll
        for (int i = 0; i < 4; ++i)
#pragma unroll
            for (int j = 0; j < 4; ++j) acc[i][j] = (f32x4){0.f, 0.f, 0.f, 0.f};

        const char* gA = (const char*)A + (size_t)m0 * rs;
        const char* gB = (const char*)W1Hp;

        auto st1 = [&](const char* g, char* l, int idx) {
            const int row = idx >> 2;
            const int kc  = (idx & 3) ^ ((row >> 1) & 3);
            gload16(g + (size_t)row * rs + (size_t)(kc << 4), l + idx * 16);
        };
        auto stage = [&](int buf, int t) {
            const size_t k0b = (size_t)t << 6;
            char* lb = lds + buf * STEPB;
            st1(gA + k0b, lb, tid);
            st1(gB + k0b, lb + 8192, tid);
            st1(gB + k0b, lb + 8192, tid + 512);
        };

        const int ra_ = wr * 64 + (lane & 15);
        const int rb_ = wc * 64 + (lane & 15);
        const int q   = lane >> 4;
        const int abase = ra_ * 64 + ((q ^ ((ra_ >> 1) & 3)) << 4);
        const int bbase = rb_ * 64 + ((q ^ ((rb_ >> 1) & 3)) << 4);

        stage(0, 0);
        stage(1, 1);

        int cur = 0;
        for (int t = 0; t < 8; ++t) {
            if (t + 1 < 8)
                asm volatile("s_waitcnt vmcnt(3)" ::: "memory");
            else
                asm volatile("s_waitcnt vmcnt(0)" ::: "memory");
            __builtin_amdgcn_sched_barrier(0);
            __builtin_amdgcn_s_barrier();
            asm volatile("" ::: "memory");

            int pf = cur + 2; if (pf >= 3) pf -= 3;
            if (t + 2 < 8) stage(pf, t + 2);

            const char* lb = lds + cur * STEPB;
            bf16x8 a4[4], b4[4];
#pragma unroll
            for (int f = 0; f < 4; ++f) {
                a4[f] = *(const bf16x8*)(lb + abase + f * 1024);
                b4[f] = *(const bf16x8*)(lb + 8192 + bbase + f * 1024);
            }
            __builtin_amdgcn_s_setprio(1);
#pragma unroll
            for (int fm = 0; fm < 4; ++fm)
#pragma unroll
                for (int fn = 0; fn < 4; ++fn)
                    acc[fm][fn] = __builtin_amdgcn_mfma_f32_16x16x32_bf16(a4[fm], b4[fn], acc[fm][fn], 0, 0, 0);
            __builtin_amdgcn_s_setprio(0);
            ++cur; if (cur >= 3) cur -= 3;
        }

        float bv[4];
#pragma unroll
        for (int fn = 0; fn < 4; ++fn) bv[fn] = b1[wc * 64 + fn * 16 + (lane & 15)];
#pragma unroll
        for (int fm = 0; fm < 4; ++fm) {
#pragma unroll
            for (int fn = 0; fn < 4; ++fn) {
                const int col = wc * 64 + fn * 16 + (lane & 15);
                const int cpart = ((col >> 5) << 6) + ((col & 7) * 2);
                const int kc = (col >> 3) & 3;
#pragma unroll
                for (int r = 0; r < 4; ++r) {
                    const int row = wr * 64 + fm * 16 + (lane >> 4) * 4 + r;
                    const float v = ftanh(acc[fm][fn][r] + bv[fn]);
                    const int byt = row * 512 + cpart + ((kc ^ ((row >> 1) & 3)) << 4);
                    *(u16*)(lds + OFFX + byt) = f2bf(v);
                }
            }
        }
    }
    __syncthreads();   // full drain: X visible to all waves

    // ================= phase 2: h2 = tanh(h1 @ W2^T + b2) =================
    f32x4 acc2[4][4];
#pragma unroll
    for (int i = 0; i < 4; ++i)
#pragma unroll
        for (int j = 0; j < 4; ++j) acc2[i][j] = (f32x4){0.f, 0.f, 0.f, 0.f};

    const int wr2 = (w >> 1) & 1, wc2 = w & 1;   // meaningful for w<4
    {
        const char* gB2 = (const char*)W2Hp;
        auto st2 = [&](int buf, int t) {
            const size_t k0b = (size_t)t << 6;
            const int row = tid >> 2;                 // 0..127
            const int kc  = (tid & 3) ^ ((row >> 1) & 3);
            gload16(gB2 + (size_t)row * rs + k0b + (size_t)(kc << 4),
                    lds + buf * STEPB + tid * 16);
        };
        st2(0, 0);
        st2(1, 1);

        const int q = lane >> 4;
        const int rb = wc2 * 64 + (lane & 15);
        const int bbase = rb * 64 + ((q ^ ((rb >> 1) & 3)) << 4);
        const int ra = wr2 * 64 + (lane & 15);
        const int abase = ra * 512 + ((q ^ ((ra >> 1) & 3)) << 4);

        int cur = 0;
        for (int t = 0; t < 8; ++t) {
            if (t + 1 < 8)
                asm volatile("s_waitcnt vmcnt(1)" ::: "memory");
            else
                asm volatile("s_waitcnt vmcnt(0)" ::: "memory");
            __builtin_amdgcn_sched_barrier(0);
            __builtin_amdgcn_s_barrier();
            asm volatile("" ::: "memory");

            int pf = cur + 2; if (pf >= 3) pf -= 3;
            if (t + 2 < 8) st2(pf, t + 2);

            if (w < 4) {
                const char* lb = lds + cur * STEPB;
                bf16x8 a4[4], b4[4];
#pragma unroll
                for (int f = 0; f < 4; ++f) {
                    a4[f] = *(const bf16x8*)(lds + OFFX + abase + f * 8192 + t * 64);
                    b4[f] = *(const bf16x8*)(lb + bbase + f * 1024);
                }
                __builtin_amdgcn_s_setprio(1);
#pragma unroll
                for (int fm = 0; fm < 4; ++fm)
#pragma unroll
                    for (int fn = 0; fn < 4; ++fn)
                        acc2[fm][fn] = __builtin_amdgcn_mfma_f32_16x16x32_bf16(a4[fm], b4[fn], acc2[fm][fn], 0, 0, 0);
                __builtin_amdgcn_s_setprio(0);
            }
            ++cur; if (cur >= 3) cur -= 3;
        }
    }

    // ================= phase 3: weighted reduction =================
    __syncthreads();
    float* rsum = (float*)lds;               // [128][2]
    float* red  = (float*)(lds + 1024);      // [256]

    if (w < 4) {
        float bv[4], wv[4];
#pragma unroll
        for (int fn = 0; fn < 4; ++fn) {
            const int col = wc2 * 64 + fn * 16 + (lane & 15);
            bv[fn] = b2[col];
            wv[fn] = Wout[col];
        }
#pragma unroll
        for (int fm = 0; fm < 4; ++fm) {
#pragma unroll
            for (int r = 0; r < 4; ++r) {
                float c = 0.f;
#pragma unroll
                for (int fn = 0; fn < 4; ++fn)
                    c += ftanh(acc2[fm][fn][r] + bv[fn]) * wv[fn];
                c += __shfl_xor(c, 1);
                c += __shfl_xor(c, 2);
                c += __shfl_xor(c, 4);
                c += __shfl_xor(c, 8);
                if ((lane & 15) == 0)
                    rsum[(wr2 * 64 + fm * 16 + (lane >> 4) * 4 + r) * 2 + wc2] = c;
            }
        }
    }
    __syncthreads();

    const float bO = bout[0];
    float val = 0.f;
    int rowb = -1;
    if (tid < 128) {
        const int gr = m0 + tid;
        if (gr < Mvalid) {
            const float dot = rsum[tid * 2] + rsum[tid * 2 + 1] + bO;
            rowb = gr / NW_;
            val = dot * wts[gr - rowb * NW_];
        }
    }
    __syncthreads();

    const int bFirst = m0 / NW_;
    if (tid < 256) red[tid] = (tid < 128 && rowb == bFirst) ? val : 0.f;
    __syncthreads();
    for (int s = 128; s > 0; s >>= 1) {
        if (tid < s) red[tid] += red[tid + s];
        __syncthreads();
    }
    if (tid == 0) partial[bm * 2] = red[0];
    __syncthreads();
    if (tid < 256) red[tid] = (tid < 128 && rowb == bFirst + 1) ? val : 0.f;
    __syncthreads();
    for (int s = 128; s > 0; s >>= 1) {
        if (tid < s) red[tid] += red[tid + s];
        __syncthreads();
    }
    if (tid == 0) partial[bm * 2 + 1] = red[0];
}

// ---------------------------------------------------------------------------
// finred: out[b0+b] = fixed-order sum of partial slots spanning batch b.
// ---------------------------------------------------------------------------
__global__ __launch_bounds__(64) void finred_kernel(const float* __restrict__ partial,
                                                    float* __restrict__ out,
                                                    int nbat, int nblocks) {
    const int b = threadIdx.x;
    if (b >= nbat) return;
    int lo = (b * NW_) / 128;
    int hi = ((b + 1) * NW_ - 1) / 128;
    if (hi > nblocks - 1) hi = nblocks - 1;
    float s = 0.f;
    for (int bm = lo; bm <= hi; ++bm) {
        const int slot = ((bm * 128) / NW_ == b) ? 0 : 1;
        s += partial[bm * 2 + slot];
    }
    out[b] = s;
}

// ---------------------------------------------------------------------------
extern "C" void kernel_launch(void* const* d_in, const int* in_sizes, int n_in,
                              void* d_out, int out_size, void* d_ws, size_t ws_size,
                              hipStream_t stream) {
    const float* x    = (const float*)d_in[0];
    const float* Wp   = (const float*)d_in[1];
    const float* bp   = (const float*)d_in[2];
    const float* W1   = (const float*)d_in[3];
    const float* b1   = (const float*)d_in[4];
    const float* W2   = (const float*)d_in[5];
    const float* b2   = (const float*)d_in[6];
    const float* Wout = (const float*)d_in[7];
    const float* bout = (const float*)d_in[8];
    const float* agg  = (const float*)d_in[9];
    float* out = (float*)d_out;

    char* wsb = (char*)d_ws;
    size_t off = 0;
    auto ra = [](size_t b) { return (b + 255) & ~(size_t)255; };
    auto alloc = [&](size_t bytes) -> char* {
        char* p = wsb + off;
        off += ra(bytes);
        return p;
    };

    u16* WpP = (u16*)alloc((size_t)MLP_ * FD_ * 2);
    u16* W1H = (u16*)alloc((size_t)HID_ * MLP_ * 2);
    u16* W2H = (u16*)alloc((size_t)HH_ * HID_ * 2);
    float* wts = (float*)alloc((size_t)NW_ * 4);

    const size_t fixed = off;
    int NB = 32;
    for (;;) {
        const size_t M = (size_t)NB * NW_;
        const size_t Mp = ((M + 127) / 128) * 128;
        const size_t need = ra(Mp * FD_ * 2) +        // featP
                            ra(Mp * 256 * 2) +        // projH
                            ra((Mp / 128) * 2 * 4);   // partial
        if (fixed + need <= ws_size || NB == 1) break;
        NB >>= 1;
    }
    const size_t Mmax  = (size_t)NB * NW_;
    const size_t MpMax = ((Mmax + 127) / 128) * 128;
    u16* featH = (u16*)alloc(MpMax * FD_ * 2);
    u16* projH = (u16*)alloc(MpMax * 256 * 2);
    float* partial = (float*)alloc((MpMax / 128) * 2 * 4);

    for (int b0 = 0; b0 < B_; b0 += NB) {
        const int nb = (B_ - b0 < NB) ? (B_ - b0) : NB;
        const int M = nb * NW_;
        const int Mp = ((M + 127) / 128) * 128;

        // merged prep (weights, softmax) + feat (TN=64), one launch
        prepfeat_kernel<<<dim3(177 + 64 * nb), dim3(256), 0, stream>>>(
            x + (size_t)b0 * C_ * T_, Wp, W1, W2, agg,
            WpP, W1H, W2H, wts, (u32*)featH);

        // proj = tanh(feat @ WpP^T + bp) * pi   (K=2112, BK=64)
        gemm64_kernel<<<dim3(Mp / 128), dim3(512), 0, stream>>>(
            featH, WpP, bp, PI_F, projH, M, FD_);

        // fused MLP tail: h1 + h2 + weighted reduce -> partials
        mlp_tail_kernel<<<dim3(Mp / 128), dim3(512), 0, stream>>>(
            projH, W1H, b1, W2H, b2, Wout, bout, wts, partial, M);

        finred_kernel<<<dim3(1), dim3(64), 0, stream>>>(
            partial, out + b0, nb, Mp / 128);
    }
}